// Round 1
// 77.173 us; speedup vs baseline: 1.2137x; 1.2137x over previous
//
#include <hip/hip_runtime.h>
#include <hip/hip_bf16.h>

// QuanvolutionGraphQLClassifier — f32 in/out. 2-kernel pipeline.
// Circuit factorizes into wires {0,1} x {2,3}; each Pauli-Z expectation is a
// bilinear form e_d = wA . H_d . wB with w(a) = (cos^2 a/2, cos a/2 sin a/2,
// sin^2 a/2) and H_d fixed 3x3 from q_params (verified R4/R5 vs statevector).
//  kA (196 blk x 256, lb(256,1)): all lanes build H redundantly in regs
//      (__sincosf, no spills); sample-0 meas one-patch-per-thread -> LDS;
//      adjacency row m; fold into W2 split 4-way per (k,d) + LDS reduce.
//  kB (B/8 blk x 256, lb(256,2)): one wave per TWO samples (shared W2 loads);
//      3-stage xor reduce + LDS finish; 16-lane-group log_softmax.
// R6 theory: timed region is dominated by the harness's 256 MiB workspace
// poison fill (~82 us, see rocprof top-5); this round compresses the
// controllable kernel tail (~10 us) — 2 samples/wave halves W2 L1 traffic,
// cheaper reduction, parallel fold in kA.

#define NP 196

__device__ __forceinline__ float quad3(const float* H, const float* wa,
                                       const float* wb) {
  return wa[0] * (H[0] * wb[0] + H[1] * wb[1] + H[2] * wb[2]) +
         wa[1] * (H[3] * wb[0] + H[4] * wb[1] + H[5] * wb[2]) +
         wa[2] * (H[6] * wb[0] + H[7] * wb[1] + H[8] * wb[2]);
}

// Builds the full H[36] (A: 0..17, B: 18..35) — wave-uniform, all regs.
__device__ __forceinline__ void build_H_all(const float* __restrict__ qp,
                                            float* __restrict__ H) {
  float qc[6], qs[6];
#pragma unroll
  for (int i = 0; i < 6; ++i) __sincosf(0.5f * qp[i], &qs[i], &qc[i]);
#pragma unroll
  for (int sub = 0; sub < 2; ++sub) {
    float Mr[4][4] = {}, Mi[4][4] = {};
    if (sub == 0) {
      // U_A = RY(q4,w0) * CNOT01 * RY(q1,w1) * RX(q0,w0); index = 2*b0 + b1
      Mr[0][0] = Mr[1][1] = Mr[2][2] = Mr[3][3] = qc[0];  // RX(q0) on w0
      Mi[0][2] = Mi[2][0] = Mi[1][3] = Mi[3][1] = -qs[0];
#pragma unroll
      for (int j = 0; j < 4; ++j) {  // RY(q1) on w1: rows (0,1),(2,3)
        float a, b;
        a = Mr[0][j]; b = Mr[1][j]; Mr[0][j] = qc[1]*a - qs[1]*b; Mr[1][j] = qs[1]*a + qc[1]*b;
        a = Mi[0][j]; b = Mi[1][j]; Mi[0][j] = qc[1]*a - qs[1]*b; Mi[1][j] = qs[1]*a + qc[1]*b;
        a = Mr[2][j]; b = Mr[3][j]; Mr[2][j] = qc[1]*a - qs[1]*b; Mr[3][j] = qs[1]*a + qc[1]*b;
        a = Mi[2][j]; b = Mi[3][j]; Mi[2][j] = qc[1]*a - qs[1]*b; Mi[3][j] = qs[1]*a + qc[1]*b;
      }
#pragma unroll
      for (int j = 0; j < 4; ++j) {  // CNOT(0,1): swap rows 2,3
        float r = Mr[2][j]; Mr[2][j] = Mr[3][j]; Mr[3][j] = r;
        float q = Mi[2][j]; Mi[2][j] = Mi[3][j]; Mi[3][j] = q;
      }
#pragma unroll
      for (int j = 0; j < 4; ++j) {  // RY(q4) on w0: rows (0,2),(1,3)
        float a, b;
        a = Mr[0][j]; b = Mr[2][j]; Mr[0][j] = qc[4]*a - qs[4]*b; Mr[2][j] = qs[4]*a + qc[4]*b;
        a = Mi[0][j]; b = Mi[2][j]; Mi[0][j] = qc[4]*a - qs[4]*b; Mi[2][j] = qs[4]*a + qc[4]*b;
        a = Mr[1][j]; b = Mr[3][j]; Mr[1][j] = qc[4]*a - qs[4]*b; Mr[3][j] = qs[4]*a + qc[4]*b;
        a = Mi[1][j]; b = Mi[3][j]; Mi[1][j] = qc[4]*a - qs[4]*b; Mi[3][j] = qs[4]*a + qc[4]*b;
      }
    } else {
      // U_B = RZ(q5,w3) * CNOT23 * RX(q3,w3) * RZ(q2,w2); index = 2*b2 + b3
      Mr[0][0] = Mr[1][1] = Mr[2][2] = Mr[3][3] = qc[2];  // RZ(q2) on w2
      Mi[0][0] = Mi[1][1] = -qs[2]; Mi[2][2] = Mi[3][3] = qs[2];
#pragma unroll
      for (int j = 0; j < 4; ++j) {  // RX(q3) on w3: rows (0,1),(2,3)
        float ra, ia, rb, ib;
        ra = Mr[0][j]; ia = Mi[0][j]; rb = Mr[1][j]; ib = Mi[1][j];
        Mr[0][j] = qc[3]*ra + qs[3]*ib;  Mi[0][j] = qc[3]*ia - qs[3]*rb;
        Mr[1][j] = qc[3]*rb + qs[3]*ia;  Mi[1][j] = qc[3]*ib - qs[3]*ra;
        ra = Mr[2][j]; ia = Mi[2][j]; rb = Mr[3][j]; ib = Mi[3][j];
        Mr[2][j] = qc[3]*ra + qs[3]*ib;  Mi[2][j] = qc[3]*ia - qs[3]*rb;
        Mr[3][j] = qc[3]*rb + qs[3]*ia;  Mi[3][j] = qc[3]*ib - qs[3]*ra;
      }
#pragma unroll
      for (int j = 0; j < 4; ++j) {  // CNOT(2,3): swap rows 2,3
        float r = Mr[2][j]; Mr[2][j] = Mr[3][j]; Mr[3][j] = r;
        float q = Mi[2][j]; Mi[2][j] = Mi[3][j]; Mi[3][j] = q;
      }
#pragma unroll
      for (int r = 0; r < 4; ++r) {  // RZ(q5) on w3: rows 0,2 *(c5-is5); 1,3 *(c5+is5)
        float sg = (r & 1) ? 1.0f : -1.0f;
#pragma unroll
        for (int j = 0; j < 4; ++j) {
          float re = Mr[r][j], im = Mi[r][j];
          Mr[r][j] = qc[5] * re - sg * qs[5] * im;
          Mi[r][j] = qc[5] * im + sg * qs[5] * re;
        }
      }
    }
    // G_d[j][k] = sum_i sigma_i (Re U_ij Re U_ik + Im U_ij Im U_ik)
#pragma unroll
    for (int d = 0; d < 2; ++d) {
      float G[4][4];
#pragma unroll
      for (int j = 0; j < 4; ++j)
#pragma unroll
        for (int k = 0; k < 4; ++k) {
          float g = 0.0f;
#pragma unroll
          for (int i = 0; i < 4; ++i) {
            float sg = (d == 0) ? ((i < 2) ? 1.f : -1.f)
                                : (((i & 1) == 0) ? 1.f : -1.f);
            g += sg * (Mr[i][j] * Mr[i][k] + Mi[i][j] * Mi[i][k]);
          }
          G[j][k] = g;
        }
      float* Hd = H + sub * 18 + d * 9;
      Hd[0] = G[0][0];       Hd[1] = 2.f * G[0][1];               Hd[2] = G[1][1];
      Hd[3] = 2.f * G[0][2]; Hd[4] = 2.f * (G[0][3] + G[1][2]);   Hd[5] = 2.f * G[1][3];
      Hd[6] = G[2][2];       Hd[7] = 2.f * G[2][3];               Hd[8] = G[3][3];
    }
  }
}

// Pauli-Z expectations of patch p of image xb, via the H bilinear forms.
__device__ __forceinline__ void meas_patch(const float* __restrict__ xb, int p,
                                           const float* __restrict__ H,
                                           float* e) {
  int i = p / 14, j = p - 14 * i;
  float2 top = *(const float2*)(xb + 56 * i + 2 * j);
  float2 bot = *(const float2*)(xb + 56 * i + 28 + 2 * j);
  float c0, s0, c1, s1, c2, s2, c3, s3;
  __sincosf(0.5f * top.x, &s0, &c0);
  __sincosf(0.5f * top.y, &s1, &c1);
  __sincosf(0.5f * bot.x, &s2, &c2);
  __sincosf(0.5f * bot.y, &s3, &c3);
  float wA0[3] = {c0 * c0, c0 * s0, s0 * s0};
  float wA1[3] = {c1 * c1, c1 * s1, s1 * s1};
  float wB0[3] = {c2 * c2, c2 * s2, s2 * s2};
  float wB1[3] = {c3 * c3, c3 * s3, s3 * s3};
  e[0] = quad3(H, wA0, wA1);
  e[1] = quad3(H + 9, wA0, wA1);
  e[2] = quad3(H + 18, wB0, wB1);
  e[3] = quad3(H + 27, wB0, wB1);
}

// ---- kA: block m: H + sample-0 meas + adjacency row m -> W2[k,4m+d] -------
__global__ __launch_bounds__(256, 1) void k_w2(const float* __restrict__ x,
                                               const float* __restrict__ qp,
                                               const float* __restrict__ W,
                                               float* __restrict__ W2,
                                               float* __restrict__ HG) {
  __shared__ float vs[NP][4];
  __shared__ float ns[NP];
  __shared__ float wrow[NP];
  __shared__ float red[160];
  int m = blockIdx.x, t = threadIdx.x;

  float H[36];
  build_H_all(qp, H);  // wave-uniform, registers only

  if (m == 0 && t == 0) {
#pragma unroll
    for (int i = 0; i < 36; ++i) HG[i] = H[i];  // constant indices
  }

  if (t < NP) {  // one patch per thread, single pass
    float e[4];
    meas_patch(x, t, H, e);
    vs[t][0] = e[0]; vs[t][1] = e[1]; vs[t][2] = e[2]; vs[t][3] = e[3];
    ns[t] = sqrtf(e[0]*e[0] + e[1]*e[1] + e[2]*e[2] + e[3]*e[3]);
  }
  __syncthreads();
  float v0 = vs[m][0], v1 = vs[m][1], v2 = vs[m][2], v3 = vs[m][3];
  float nm = ns[m];
  if (t < NP) {
    float dot = v0 * vs[t][0] + v1 * vs[t][1] + v2 * vs[t][2] + v3 * vs[t][3];
    float sim = dot / (nm * ns[t] + 1e-12f);  // symmetric => adj[t,m]
    wrow[t] = (sim >= 0.9f) ? 1.0f : ((sim >= 0.5f) ? 0.5f : 0.0f);
  }
  __syncthreads();
  if (t < 160) {  // 40 (k,d) pairs x 4 chunks of 49
    int pair = t >> 2, chunk = t & 3;
    int k = pair >> 2, d = pair & 3;
    const float* Wk = W + k * 784 + d;
    float acc = 0.0f;
    int n0 = chunk * 49;
#pragma unroll 7
    for (int n = n0; n < n0 + 49; ++n) acc += wrow[n] * Wk[4 * n];
    red[t] = acc;
  }
  __syncthreads();
  if (t < 40) {
    int k = t >> 2, d = t & 3;
    W2[k * 784 + 4 * m + d] = red[4*t] + red[4*t+1] + red[4*t+2] + red[4*t+3];
  }
}

// ---- kB: one wave per TWO samples -----------------------------------------
__global__ __launch_bounds__(256, 2) void k_main(const float* __restrict__ x,
                                                 const float* __restrict__ HG,
                                                 const float* __restrict__ bias,
                                                 const float* __restrict__ W2,
                                                 float* __restrict__ out,
                                                 int Bsz) {
  __shared__ float red[4][160];  // per wave: [sample 0|1][k 0..9][8 partials]
  int t = threadIdx.x, wv = t >> 6, lane = t & 63;
  int b0 = blockIdx.x * 8 + wv * 2;
  bool vA = b0 < Bsz, vB = (b0 + 1) < Bsz;

  float H[36];
#pragma unroll
  for (int i = 0; i < 36; ++i) H[i] = HG[i];  // uniform -> scalar loads

  const float* xa = x + (size_t)b0 * 784;
  const float* xb = xa + 784;
  float accA[10], accB[10];
#pragma unroll
  for (int k = 0; k < 10; ++k) { accA[k] = 0.0f; accB[k] = 0.0f; }

#pragma unroll
  for (int r = 0; r < 4; ++r) {
    int p = lane + 64 * r;
    if (p < NP) {
      float eA[4] = {0.f, 0.f, 0.f, 0.f};
      float eB[4] = {0.f, 0.f, 0.f, 0.f};
      if (vA) meas_patch(xa, p, H, eA);
      if (vB) meas_patch(xb, p, H, eB);
#pragma unroll
      for (int k = 0; k < 10; ++k) {  // one W2 load feeds both samples
        float4 w = *(const float4*)(W2 + k * 784 + 4 * p);
        accA[k] += eA[0] * w.x + eA[1] * w.y + eA[2] * w.z + eA[3] * w.w;
        accB[k] += eB[0] * w.x + eB[1] * w.y + eB[2] * w.z + eB[3] * w.w;
      }
    }
  }

  // 3-stage xor reduce: every lane l ends with partial over lanes ≡ l (mod 8)
#pragma unroll
  for (int k = 0; k < 10; ++k) {
#pragma unroll
    for (int off = 32; off >= 8; off >>= 1) {
      accA[k] += __shfl_xor(accA[k], off);
      accB[k] += __shfl_xor(accB[k], off);
    }
  }
  if (lane < 8) {
#pragma unroll
    for (int k = 0; k < 10; ++k) {
      red[wv][k * 8 + lane]      = accA[k];
      red[wv][80 + k * 8 + lane] = accB[k];
    }
  }
  __syncthreads();

  // lanes 0..9 -> sample A logits, lanes 32..41 -> sample B logits
  int s = lane >> 5;
  int k10 = lane & 31;
  float lg = -1e30f;
  if (k10 < 10) {
    const float4* q = (const float4*)&red[wv][s * 80 + k10 * 8];
    float4 a = q[0], b4 = q[1];
    lg = ((a.x + a.y) + (a.z + a.w)) + ((b4.x + b4.y) + (b4.z + b4.w)) +
         bias[k10];
  }
  // 16-lane-group log_softmax (xor 8/4/2/1 stays within aligned 16-groups)
  float mx = lg;
#pragma unroll
  for (int off = 8; off; off >>= 1) mx = fmaxf(mx, __shfl_xor(mx, off));
  float ex = (k10 < 10) ? __expf(lg - mx) : 0.0f;
  float sm = ex;
#pragma unroll
  for (int off = 8; off; off >>= 1) sm += __shfl_xor(sm, off);
  float lse = mx + __logf(sm);
  bool vs_ = s ? vB : vA;
  if (k10 < 10 && vs_) out[(size_t)(b0 + s) * 10 + k10] = lg - lse;
}

extern "C" void kernel_launch(void* const* d_in, const int* in_sizes, int n_in,
                              void* d_out, int out_size, void* d_ws, size_t ws_size,
                              hipStream_t stream) {
  const float* x  = (const float*)d_in[0];  // (B,1,28,28) f32
  const float* qp = (const float*)d_in[1];  // (6,) f32
  const float* W  = (const float*)d_in[2];  // (10,784) f32
  const float* bi = (const float*)d_in[3];  // (10,) f32
  float* out = (float*)d_out;               // (B,10) f32

  int Bsz = in_sizes[0] / 784;

  float* W2 = (float*)d_ws;   // 7840 f32
  float* HG = W2 + 7840;      // 36 f32

  k_w2<<<NP, 256, 0, stream>>>(x, qp, W, W2, HG);
  k_main<<<(Bsz + 7) / 8, 256, 0, stream>>>(x, HG, bi, W2, out, Bsz);
}